// Round 7
// baseline (86.552 us; speedup 1.0000x reference)
//
#include <hip/hip_runtime.h>
#include <hip/hip_bf16.h>
#include <stdint.h>

// CACProjector: logits = x @ W^T ; dist = sqrt(max(||row||^2 - 2*A*logit + A^2, 0))
// Round 7: single fused GEMM+distance kernel. BM=64, BN=N=1024 (block owns full
// rows): x read ONCE (in-kernel f32->bf16, 2-Ktile-deep reg staging), W bf16 read
// from global/L2 (no B-LDS), distances from accumulators (no logits re-read).

#define M_DIM 16384
#define N_DIM 1024
#define K_DIM 768
#define ALPHA_F 10.0f

typedef __bf16 bf16x8 __attribute__((ext_vector_type(8)));
typedef float f32x4 __attribute__((ext_vector_type(4)));

#define LGKM0 asm volatile("s_waitcnt lgkmcnt(0)" ::: "memory")
#define PRIO1 __builtin_amdgcn_s_setprio(1)
#define PRIO0 __builtin_amdgcn_s_setprio(0)

static __device__ __forceinline__ void bar() {
  asm volatile("" ::: "memory");
  __builtin_amdgcn_s_barrier();
  asm volatile("" ::: "memory");
}

// ---------------- W fp32 -> bf16 (tiny: 3MB read) ----------------
__global__ __launch_bounds__(256) void cvt_w_kernel(const float* __restrict__ in,
                                                    unsigned short* __restrict__ out) {
  int i = blockIdx.x * 256 + threadIdx.x;  // grid 768 covers N*K/4 exactly
  f32x4 v = reinterpret_cast<const f32x4*>(in)[i];
  union { __bf16 h[4]; ushort4 u; } p;
  p.h[0] = (__bf16)v[0]; p.h[1] = (__bf16)v[1];
  p.h[2] = (__bf16)v[2]; p.h[3] = (__bf16)v[3];
  reinterpret_cast<ushort4*>(out)[i] = p.u;
}

// ---------------- fused GEMM + distance ----------------
// 512 threads = 8 waves; wave w owns cols [w*128, w*128+128), all 64 rows.
// A-LDS: 3 buffers of [64 rows][64 k] bf16 (8 KB each), 16B-slot XOR swizzle
// (slot cs of row holds col16 cs^(row&7)); staged via regs (f32 global -> cvt ->
// linear ds_write slot=t), issue at kt, write at kt+2 => ~2 K-tiles latency cover.
// B: bf16x8 fragments loaded per K-step straight from Wb (1.5 MB, L2-resident).
// One LGKM0+barrier per K-step. Epilogue: row sumsq via 16-lane shuffle +
// cross-wave LDS reduce; logits and dist both written from acc.
__global__ __launch_bounds__(512, 2) void fused_kernel(
    const float* __restrict__ X,            // 16384 x 768 f32
    const unsigned short* __restrict__ Wb,  // 1024 x 768 bf16 bits
    float* __restrict__ logits,             // 16384 x 1024
    float* __restrict__ dist) {             // 16384 x 1024
  __shared__ __align__(16) unsigned short ldsA[3][64 * 64];  // 24 KB
  __shared__ float rs[64][8];                                // 2 KB

  const int t = threadIdx.x;
  const int lane = t & 63;
  const int w = t >> 6;
  const int tm = blockIdx.x;  // 256 blocks = 1/CU

  const float* Xb = X + (size_t)tm * 64 * K_DIM;

  // A staging geometry: slot t -> row=t>>3, slot-col cs=t&7; source col16 = cs^(row&7)
  const int srow = t >> 3, scs = t & 7;
  const float* sgp = Xb + (size_t)srow * K_DIM + (scs ^ (srow & 7)) * 8;

  auto cvt8 = [&](f32x4 a, f32x4 b) -> bf16x8 {
    union { __bf16 h[8]; bf16x8 v; } p;
    p.h[0] = (__bf16)a[0]; p.h[1] = (__bf16)a[1];
    p.h[2] = (__bf16)a[2]; p.h[3] = (__bf16)a[3];
    p.h[4] = (__bf16)b[0]; p.h[5] = (__bf16)b[1];
    p.h[6] = (__bf16)b[2]; p.h[7] = (__bf16)b[3];
    return p.v;
  };

  f32x4 acc[4][8] = {};

  const unsigned short* wbase =
      Wb + (size_t)(w * 128 + (lane & 15)) * K_DIM + (lane >> 4) * 8;

  f32x4 ra0, ra1, rb0, rb1;  // two reg-stage buffers (even kt / odd kt)

  // Prologue: stage A(0),A(1) through regs; issue A(2),A(3).
  { const f32x4* p = (const f32x4*)(sgp + 0 * 64); ra0 = p[0]; ra1 = p[1]; }
  { const f32x4* p = (const f32x4*)(sgp + 1 * 64); rb0 = p[0]; rb1 = p[1]; }
  *(bf16x8*)(&ldsA[0][0] + t * 8) = cvt8(ra0, ra1);
  *(bf16x8*)(&ldsA[1][0] + t * 8) = cvt8(rb0, rb1);
  { const f32x4* p = (const f32x4*)(sgp + 2 * 64); ra0 = p[0]; ra1 = p[1]; }
  { const f32x4* p = (const f32x4*)(sgp + 3 * 64); rb0 = p[0]; rb1 = p[1]; }
  LGKM0;
  bar();

#pragma unroll
  for (int kt = 0; kt < 12; ++kt) {
    const unsigned short* Lbuf = &ldsA[kt % 3][0];
    // B fragments for this K-step (16 loads, L2-hot, hoisted by compiler)
    bf16x8 bq[8][2];
    const unsigned short* wp = wbase + kt * 64;
#pragma unroll
    for (int ni = 0; ni < 8; ++ni) {
      bq[ni][0] = *(const bf16x8*)(wp + (size_t)ni * 16 * K_DIM);
      bq[ni][1] = *(const bf16x8*)(wp + (size_t)ni * 16 * K_DIM + 32);
    }
#pragma unroll
    for (int mi = 0; mi < 4; ++mi) {
      int row = mi * 16 + (lane & 15);
      bf16x8 af0 = *(const bf16x8*)(Lbuf + row * 64 + (((lane >> 4)) ^ (row & 7)) * 8);
      bf16x8 af1 = *(const bf16x8*)(Lbuf + row * 64 + ((4 + (lane >> 4)) ^ (row & 7)) * 8);
      PRIO1;
#pragma unroll
      for (int ni = 0; ni < 8; ++ni) {
        acc[mi][ni] = __builtin_amdgcn_mfma_f32_16x16x32_bf16(af0, bq[ni][0], acc[mi][ni], 0, 0, 0);
        acc[mi][ni] = __builtin_amdgcn_mfma_f32_16x16x32_bf16(af1, bq[ni][1], acc[mi][ni], 0, 0, 0);
      }
      PRIO0;
    }
    // stage path: write A(kt+2) (issued 2 kt ago), issue A(kt+4)
    if (kt <= 9) {
      if ((kt & 1) == 0) *(bf16x8*)(&ldsA[(kt + 2) % 3][0] + t * 8) = cvt8(ra0, ra1);
      else               *(bf16x8*)(&ldsA[(kt + 2) % 3][0] + t * 8) = cvt8(rb0, rb1);
    }
    if (kt <= 7) {
      const f32x4* p = (const f32x4*)(sgp + (kt + 4) * 64);
      if ((kt & 1) == 0) { ra0 = p[0]; ra1 = p[1]; }
      else               { rb0 = p[0]; rb1 = p[1]; }
    }
    LGKM0;
    bar();
  }

  // ---- epilogue: per-row sumsq ----
  float part[4][4];
#pragma unroll
  for (int mi = 0; mi < 4; ++mi)
#pragma unroll
    for (int j = 0; j < 4; ++j) {
      float s = 0.f;
#pragma unroll
      for (int ni = 0; ni < 8; ++ni) { float v = acc[mi][ni][j]; s += v * v; }
      part[mi][j] = s;
    }
#pragma unroll
  for (int m = 1; m <= 8; m <<= 1)
#pragma unroll
    for (int mi = 0; mi < 4; ++mi)
#pragma unroll
      for (int j = 0; j < 4; ++j)
        part[mi][j] += __shfl_xor(part[mi][j], m, 64);
  if ((lane & 15) == 0) {
    int q = lane >> 4;
#pragma unroll
    for (int mi = 0; mi < 4; ++mi)
#pragma unroll
      for (int j = 0; j < 4; ++j)
        rs[mi * 16 + q * 4 + j][w] = part[mi][j];
  }
  __syncthreads();

  float S[4][4];
#pragma unroll
  for (int mi = 0; mi < 4; ++mi)
#pragma unroll
    for (int j = 0; j < 4; ++j) {
      int row = mi * 16 + (lane >> 4) * 4 + j;
      f32x4 a = *(const f32x4*)&rs[row][0];
      f32x4 b = *(const f32x4*)&rs[row][4];
      S[mi][j] = (a[0] + a[1] + a[2] + a[3]) + (b[0] + b[1] + b[2] + b[3]);
    }

  // ---- write logits + dist ----
  float* Lb = logits + (size_t)tm * 64 * N_DIM + w * 128;
  float* Db = dist + (size_t)tm * 64 * N_DIM + w * 128;
  const float a2 = ALPHA_F * ALPHA_F;
#pragma unroll
  for (int mi = 0; mi < 4; ++mi)
#pragma unroll
    for (int ni = 0; ni < 8; ++ni) {
      int col = ni * 16 + (lane & 15);
      int row0 = mi * 16 + ((lane >> 4) << 2);
#pragma unroll
      for (int r = 0; r < 4; ++r) {
        float lv = acc[mi][ni][r];
        Lb[(size_t)(row0 + r) * N_DIM + col] = lv;
        float d2 = S[mi][r] - 2.0f * ALPHA_F * lv + a2;
        Db[(size_t)(row0 + r) * N_DIM + col] = sqrtf(fmaxf(d2, 0.0f));
      }
    }
}

extern "C" void kernel_launch(void* const* d_in, const int* in_sizes, int n_in,
                              void* d_out, int out_size, void* d_ws, size_t ws_size,
                              hipStream_t stream) {
  const float* x = (const float*)d_in[0];  // 16384 x 768
  const float* W = (const float*)d_in[1];  // 1024 x 768
  float* logits = (float*)d_out;
  float* dist = logits + (size_t)M_DIM * N_DIM;

  unsigned short* Wb = (unsigned short*)d_ws;  // 1.5 MB

  cvt_w_kernel<<<N_DIM * K_DIM / 4 / 256, 256, 0, stream>>>(W, Wb);
  fused_kernel<<<M_DIM / 64, 512, 0, stream>>>(x, Wb, logits, dist);
}

// Round 8
// 73.236 us; speedup vs baseline: 1.1818x; 1.1818x over previous
//
#include <hip/hip_runtime.h>
#include <hip/hip_bf16.h>
#include <stdint.h>

// CACProjector round 8: fully fused GEMM+distance, latency fixed.
// Block = 64 rows x full N=1024. x-tile staged ONCE to LDS (96KB bf16, XOR swizzle);
// W streamed via global_load_lds double-buffer (2x32KB, counted vmcnt, 2-deep);
// logits chunks written during the loop; dist from acc + cross-wave sumsq reduce.

#define M_DIM 16384
#define N_DIM 1024
#define K_DIM 768
#define ALPHA_F 10.0f

typedef __bf16 bf16x8 __attribute__((ext_vector_type(8)));
typedef float f32x4 __attribute__((ext_vector_type(4)));
typedef const __attribute__((address_space(1))) void* gas_ptr;
typedef __attribute__((address_space(3))) void* las_ptr;

#define WAITV(N) asm volatile("s_waitcnt vmcnt(" #N ")" ::: "memory")
#define LGKM0 asm volatile("s_waitcnt lgkmcnt(0)" ::: "memory")
#define PRIO1 __builtin_amdgcn_s_setprio(1)
#define PRIO0 __builtin_amdgcn_s_setprio(0)

static __device__ __forceinline__ void bar() {
  asm volatile("" ::: "memory");
  __builtin_amdgcn_s_barrier();
  asm volatile("" ::: "memory");
}

static __device__ __forceinline__ bf16x8 cvt8(f32x4 a, f32x4 b) {
  union { __bf16 h[8]; bf16x8 v; } p;
  p.h[0] = (__bf16)a[0]; p.h[1] = (__bf16)a[1];
  p.h[2] = (__bf16)a[2]; p.h[3] = (__bf16)a[3];
  p.h[4] = (__bf16)b[0]; p.h[5] = (__bf16)b[1];
  p.h[6] = (__bf16)b[2]; p.h[7] = (__bf16)b[3];
  return p.v;
}

// ---------------- W fp32 -> bf16 (tiny: 3MB read) ----------------
__global__ __launch_bounds__(256) void cvt_w_kernel(const float* __restrict__ in,
                                                    unsigned short* __restrict__ out) {
  int i = blockIdx.x * 256 + threadIdx.x;  // grid 768 covers N*K/4 exactly
  f32x4 v = reinterpret_cast<const f32x4*>(in)[i];
  union { __bf16 h[4]; ushort4 u; } p;
  p.h[0] = (__bf16)v[0]; p.h[1] = (__bf16)v[1];
  p.h[2] = (__bf16)v[2]; p.h[3] = (__bf16)v[3];
  reinterpret_cast<ushort4*>(out)[i] = p.u;
}

// ---------------- fused kernel ----------------
// 512 threads = 8 waves (wr=w>>2: 32-row half; wc=w&3: 64-col quarter of chunk).
// LDS: xt[64][768] bf16 96KB + wt[2][256][64] bf16 64KB = 160KB (1 block/CU).
// Swizzle (both tiles): 16B-slot s of row holds col16 s^(row&7).
__global__ __launch_bounds__(512, 2) void fused_kernel(
    const float* __restrict__ X,            // 16384 x 768 f32
    const unsigned short* __restrict__ Wb,  // 1024 x 768 bf16 bits
    float* __restrict__ logits,             // 16384 x 1024
    float* __restrict__ dist) {             // 16384 x 1024
  __shared__ __align__(16) unsigned short xt[64 * 768];
  __shared__ __align__(16) unsigned short wt[2][256 * 64];

  const int t = threadIdx.x;
  const int lane = t & 63;
  const int w = t >> 6;
  const int wr = w >> 2;   // 0..1
  const int wc = w & 3;    // 0..3
  const int q = lane >> 4; // 0..3
  const int l15 = lane & 15;

  const int tm = blockIdx.x;  // 256 blocks = 1/CU
  const float* Xb = X + (size_t)tm * 64 * K_DIM;

  // W staging geometry: slots t+512j -> row rb+64j, slot-col csw; source col16 ccw
  const int rb = t >> 3, csw = t & 7;
  const int ccw = csw ^ (rb & 7);

  auto stage_w = [&](int buf, int nc, int kt) {
#pragma unroll
    for (int j = 0; j < 4; ++j) {
      int row = rb + 64 * j;
      const unsigned short* g =
          Wb + (size_t)(nc * 256 + row) * K_DIM + kt * 64 + ccw * 8;
      __builtin_amdgcn_global_load_lds((gas_ptr)g,
                                       (las_ptr)(&wt[buf][0] + row * 64 + csw * 8),
                                       16, 0, 0);
    }
  };

  // Prologue: W(c0,k0)->wt0, W(c0,k1)->wt1 in flight during x staging.
  stage_w(0, 0, 0);
  stage_w(1, 0, 1);

  // x staging: 64x768 f32 -> bf16 LDS, swizzled. 12 rounds x 512 threads x 8 floats.
#pragma unroll
  for (int r = 0; r < 12; ++r) {
    int id = r * 512 + t;
    int row = id / 96;
    int sc = id - row * 96;
    const f32x4* g = (const f32x4*)(Xb + (size_t)row * K_DIM + sc * 8);
    f32x4 a = g[0], b = g[1];
    *(bf16x8*)(&xt[row * 768 + (sc ^ (row & 7)) * 8]) = cvt8(a, b);
  }
  LGKM0;
  WAITV(0);
  bar();

  f32x4 acc[4][2][4] = {};  // [nc][mi][ni] -- all indices compile-time (nc unrolled)

#pragma unroll
  for (int nc = 0; nc < 4; ++nc) {
#pragma unroll 1
    for (int kt = 0; kt < 12; ++kt) {
      const int it = nc * 12 + kt;
      const int buf = kt & 1;
      // ---- fragment reads (LDS) ----
      bf16x8 af[2][2], bq[4][2];
#pragma unroll
      for (int mi = 0; mi < 2; ++mi) {
        int row = wr * 32 + mi * 16 + l15;
#pragma unroll
        for (int kk = 0; kk < 2; ++kk)
          af[mi][kk] = *(const bf16x8*)(&xt[row * 768 +
                        ((kt * 8 + kk * 4 + q) ^ (row & 7)) * 8]);
      }
#pragma unroll
      for (int ni = 0; ni < 4; ++ni) {
        int roww = wc * 64 + ni * 16 + l15;
#pragma unroll
        for (int kk = 0; kk < 2; ++kk)
          bq[ni][kk] = *(const bf16x8*)(&wt[buf][0] + roww * 64 +
                        ((kk * 4 + q) ^ (roww & 7)) * 8);
      }
      LGKM0;
      bar();  // all waves done reading wt[buf] -> safe to overwrite
      if (it + 2 < 48) {
        int itn = it + 2;
        int ncn = itn / 12;
        stage_w(buf, ncn, itn - ncn * 12);
      }
      PRIO1;
#pragma unroll
      for (int mi = 0; mi < 2; ++mi)
#pragma unroll
        for (int ni = 0; ni < 4; ++ni)
#pragma unroll
          for (int kk = 0; kk < 2; ++kk)
            acc[nc][mi][ni] = __builtin_amdgcn_mfma_f32_16x16x32_bf16(
                af[mi][kk], bq[ni][kk], acc[nc][mi][ni], 0, 0, 0);
      PRIO0;
      if (it == 46) { WAITV(0); }
      else if (it < 46) { WAITV(4); }
      if (it < 47) bar();
    }
    // write logits chunk nc (0..2) during the loop; chunk 3 in epilogue
    if (nc < 3) {
      float* Lb = logits + ((size_t)tm * 64 + wr * 32) * N_DIM + nc * 256 + wc * 64;
#pragma unroll
      for (int mi = 0; mi < 2; ++mi)
#pragma unroll
        for (int ni = 0; ni < 4; ++ni) {
          int col = ni * 16 + l15;
          int row0 = mi * 16 + q * 4;
#pragma unroll
          for (int r = 0; r < 4; ++r)
            Lb[(size_t)(row0 + r) * N_DIM + col] = acc[nc][mi][ni][r];
        }
    }
  }

  // ---- epilogue: per-row sumsq across full N ----
  float part[2][4];
#pragma unroll
  for (int mi = 0; mi < 2; ++mi)
#pragma unroll
    for (int j = 0; j < 4; ++j) {
      float s = 0.f;
#pragma unroll
      for (int nc = 0; nc < 4; ++nc)
#pragma unroll
        for (int ni = 0; ni < 4; ++ni) {
          float v = acc[nc][mi][ni][j];
          s += v * v;
        }
      part[mi][j] = s;
    }
#pragma unroll
  for (int m = 1; m <= 8; m <<= 1)
#pragma unroll
    for (int mi = 0; mi < 2; ++mi)
#pragma unroll
      for (int j = 0; j < 4; ++j)
        part[mi][j] += __shfl_xor(part[mi][j], m, 64);

  bar();  // all waves done with wt reads -> overlay rs on wt
  float* rs = (float*)&wt[0][0];  // [64 rows][4 wc]
  if (l15 == 0) {
#pragma unroll
    for (int mi = 0; mi < 2; ++mi)
#pragma unroll
      for (int j = 0; j < 4; ++j)
        rs[(wr * 32 + mi * 16 + q * 4 + j) * 4 + wc] = part[mi][j];
  }
  __syncthreads();

  float S[2][4];
#pragma unroll
  for (int mi = 0; mi < 2; ++mi)
#pragma unroll
    for (int j = 0; j < 4; ++j) {
      f32x4 v = *(const f32x4*)&rs[(wr * 32 + mi * 16 + q * 4 + j) * 4];
      S[mi][j] = (v[0] + v[1]) + (v[2] + v[3]);
    }

  // ---- write logits chunk 3 + all distances ----
  const float a2 = ALPHA_F * ALPHA_F;
  {
    float* Lb = logits + ((size_t)tm * 64 + wr * 32) * N_DIM + 3 * 256 + wc * 64;
#pragma unroll
    for (int mi = 0; mi < 2; ++mi)
#pragma unroll
      for (int ni = 0; ni < 4; ++ni) {
        int col = ni * 16 + l15;
        int row0 = mi * 16 + q * 4;
#pragma unroll
        for (int r = 0; r < 4; ++r)
          Lb[(size_t)(row0 + r) * N_DIM + col] = acc[3][mi][ni][r];
      }
  }
#pragma unroll
  for (int nc = 0; nc < 4; ++nc) {
    float* Db = dist + ((size_t)tm * 64 + wr * 32) * N_DIM + nc * 256 + wc * 64;
#pragma unroll
    for (int mi = 0; mi < 2; ++mi)
#pragma unroll
      for (int ni = 0; ni < 4; ++ni) {
        int col = ni * 16 + l15;
        int row0 = mi * 16 + q * 4;
#pragma unroll
        for (int r = 0; r < 4; ++r) {
          float lv = acc[nc][mi][ni][r];
          float d2 = S[mi][r] - 2.0f * ALPHA_F * lv + a2;
          Db[(size_t)(row0 + r) * N_DIM + col] = sqrtf(fmaxf(d2, 0.0f));
        }
      }
  }
}

extern "C" void kernel_launch(void* const* d_in, const int* in_sizes, int n_in,
                              void* d_out, int out_size, void* d_ws, size_t ws_size,
                              hipStream_t stream) {
  const float* x = (const float*)d_in[0];  // 16384 x 768
  const float* W = (const float*)d_in[1];  // 1024 x 768
  float* logits = (float*)d_out;
  float* dist = logits + (size_t)M_DIM * N_DIM;

  unsigned short* Wb = (unsigned short*)d_ws;  // 1.5 MB

  cvt_w_kernel<<<N_DIM * K_DIM / 4 / 256, 256, 0, stream>>>(W, Wb);
  fused_kernel<<<M_DIM / 64, 512, 0, stream>>>(x, Wb, logits, dist);
}